// Round 5
// baseline (105.865 us; speedup 1.0000x reference)
//
#include <hip/hip_runtime.h>
#include <math.h>

// Problem constants (from reference)
#define B_SZ 8192
#define L_SZ 50
#define D_SZ 128
#define C_SZ 256        // output cols of W_cpr
#define K_SZ 256        // = 2*D, GEMM K
#define R_SZ 7
#define BR   8          // batch rows per block (1 per wave)
#define NT   512        // 8 waves

// ---------------------------------------------------------------------------
// Kernel 0: transpose W_cpr [C][K] -> Wt [K][C], LDS-tiled (both sides
// coalesced). 64 blocks x 256 threads; 256 KB total, ~2 us.
// ---------------------------------------------------------------------------
__global__ __launch_bounds__(256) void k_transpose(const float* __restrict__ W,
                                                   float* __restrict__ Wt) {
    __shared__ float t[32][33];
    const int tx = threadIdx.x & 31;
    const int ty = threadIdx.x >> 5;  // 0..7
    const int k0 = blockIdx.x * 32;
    const int c0 = blockIdx.y * 32;
#pragma unroll
    for (int i = 0; i < 32; i += 8)
        t[ty + i][tx] = W[(size_t)(c0 + ty + i) * K_SZ + k0 + tx];
    __syncthreads();
#pragma unroll
    for (int i = 0; i < 32; i += 8)
        Wt[(size_t)(k0 + ty + i) * C_SZ + c0 + tx] = t[tx][ty + i];
}

// ---------------------------------------------------------------------------
// Fused kernel: masked embedding-bag sums (to LDS) + GEMM + LeakyReLU +
// 7-wide head + log-softmax.
//
// 512 threads = 8 waves; wave w owns batch row (row0 + w). Gather pops up to
// 4 tokens per side per iteration via two half-wave float4 loads per side
// (4 x 1 KB in flight per wave). Grid 1024 -> 4 blocks/CU x 8 waves = 32
// waves/CU (100% occupancy) to maximize memory-level parallelism on the
// random emb gather.
// ---------------------------------------------------------------------------
__global__ __launch_bounds__(512, 8) void k_fused(
    const int* __restrict__ ltok, const int* __restrict__ rtok,
    const int* __restrict__ lmask, const int* __restrict__ rmask,
    const float* __restrict__ emb, const float* __restrict__ Wt,
    const float* __restrict__ b_cpr, const float* __restrict__ W_sm,
    const float* __restrict__ b_sm, float* __restrict__ out) {

    __shared__ float X_lds[BR][K_SZ];        // 8 KB
    __shared__ float h_lds[BR][C_SZ + 4];    // 8.3 KB, padded, 16B-aligned rows
    __shared__ float part[BR][R_SZ][4];
    __shared__ float l_lds[BR][R_SZ];

    const int tid = threadIdx.x;
    const int wave = tid >> 6;
    const int lane = tid & 63;
    const int hlane = lane & 31;
    const int row0 = blockIdx.x * BR;

    // ---------------- gather phase (1 row per wave) ----------------
    const int r = row0 + wave;
    int lt = 0, lm = 0, rt = 0, rm = 0;
    if (lane < L_SZ) {
        const size_t o = (size_t)r * L_SZ + lane;
        lt = ltok[o]; lm = lmask[o]; rt = rtok[o]; rm = rmask[o];
    }
    unsigned long long bL = __ballot(lm != 0);
    unsigned long long bR = __ballot(rm != 0);

    const float4* emb4 = (const float4*)emb;  // [V][32] float4
    float4 aL0 = {0, 0, 0, 0}, aL1 = {0, 0, 0, 0};
    float4 aR0 = {0, 0, 0, 0}, aR1 = {0, 0, 0, 0};

    // Pop up to 2 tokens of a stream: lanes 0-31 take the 1st set bit's
    // token (full row as 32 float4s), lanes 32-63 the 2nd (scale 0 if odd).
#define POP2(bal, tok, e, sc, hv)                                   \
    {                                                               \
        hv = (bal != 0);                                            \
        if (hv) {                                                   \
            int i1 = __ffsll(bal) - 1; bal &= bal - 1;              \
            bool has2 = (bal != 0);                                 \
            int i2 = has2 ? (__ffsll(bal) - 1) : i1;                \
            if (has2) bal &= bal - 1;                               \
            int ts = __shfl(tok, (lane < 32) ? i1 : i2);            \
            e = emb4[((unsigned)ts << 5) + hlane];                  \
            sc = (lane < 32 || has2) ? 1.f : 0.f;                   \
        }                                                           \
    }

    while (bL | bR) {
        float4 e0, e1, e2, e3;
        float s0, s1, s2, s3;
        bool h0, h1, h2, h3;
        POP2(bL, lt, e0, s0, h0)   // left tokens 1,2
        POP2(bL, lt, e1, s1, h1)   // left tokens 3,4
        POP2(bR, rt, e2, s2, h2)   // right tokens 1,2
        POP2(bR, rt, e3, s3, h3)   // right tokens 3,4
        if (h0) { aL0.x = fmaf(s0, e0.x, aL0.x); aL0.y = fmaf(s0, e0.y, aL0.y);
                  aL0.z = fmaf(s0, e0.z, aL0.z); aL0.w = fmaf(s0, e0.w, aL0.w); }
        if (h1) { aL1.x = fmaf(s1, e1.x, aL1.x); aL1.y = fmaf(s1, e1.y, aL1.y);
                  aL1.z = fmaf(s1, e1.z, aL1.z); aL1.w = fmaf(s1, e1.w, aL1.w); }
        if (h2) { aR0.x = fmaf(s2, e2.x, aR0.x); aR0.y = fmaf(s2, e2.y, aR0.y);
                  aR0.z = fmaf(s2, e2.z, aR0.z); aR0.w = fmaf(s2, e2.w, aR0.w); }
        if (h3) { aR1.x = fmaf(s3, e3.x, aR1.x); aR1.y = fmaf(s3, e3.y, aR1.y);
                  aR1.z = fmaf(s3, e3.z, aR1.z); aR1.w = fmaf(s3, e3.w, aR1.w); }
    }
#undef POP2

    aL0.x += aL1.x; aL0.y += aL1.y; aL0.z += aL1.z; aL0.w += aL1.w;
    aR0.x += aR1.x; aR0.y += aR1.y; aR0.z += aR1.z; aR0.w += aR1.w;

    // cross-half reduce: both halves end with the full token sum
#define XHALF(a)                          \
    a.x += __shfl_xor(a.x, 32);           \
    a.y += __shfl_xor(a.y, 32);           \
    a.z += __shfl_xor(a.z, 32);           \
    a.w += __shfl_xor(a.w, 32);
    XHALF(aL0) XHALF(aR0)
#undef XHALF

    // X row: floats [0,128) = left sum, [128,256) = right sum.
    // float4 slot `lane`: lanes 0-31 left chunk hlane, 32-63 right chunk hlane.
    {
        float4* x0 = (float4*)&X_lds[wave][0];
        x0[lane] = (lane < 32) ? aL0 : aR0;
    }
    __syncthreads();

    // ---------------- GEMM phase ----------------
    // 512 threads = 64 col-groups x 8 row-groups; acc[4] per thread.
    const int cc = (tid & 63) * 4;   // 4 output cols
    const int rr = tid >> 6;         // 1 row
    float acc[4] = {0.f, 0.f, 0.f, 0.f};
#pragma unroll 4
    for (int k = 0; k < K_SZ; k += 4) {
        float4 w0 = *(const float4*)&Wt[(k + 0) * C_SZ + cc];
        float4 w1 = *(const float4*)&Wt[(k + 1) * C_SZ + cc];
        float4 w2 = *(const float4*)&Wt[(k + 2) * C_SZ + cc];
        float4 w3 = *(const float4*)&Wt[(k + 3) * C_SZ + cc];
        float4 xv = *(const float4*)&X_lds[rr][k];   // wave-uniform broadcast
        acc[0] = fmaf(xv.x, w0.x, acc[0]); acc[1] = fmaf(xv.x, w0.y, acc[1]);
        acc[2] = fmaf(xv.x, w0.z, acc[2]); acc[3] = fmaf(xv.x, w0.w, acc[3]);
        acc[0] = fmaf(xv.y, w1.x, acc[0]); acc[1] = fmaf(xv.y, w1.y, acc[1]);
        acc[2] = fmaf(xv.y, w1.z, acc[2]); acc[3] = fmaf(xv.y, w1.w, acc[3]);
        acc[0] = fmaf(xv.z, w2.x, acc[0]); acc[1] = fmaf(xv.z, w2.y, acc[1]);
        acc[2] = fmaf(xv.z, w2.z, acc[2]); acc[3] = fmaf(xv.z, w2.w, acc[3]);
        acc[0] = fmaf(xv.w, w3.x, acc[0]); acc[1] = fmaf(xv.w, w3.y, acc[1]);
        acc[2] = fmaf(xv.w, w3.z, acc[2]); acc[3] = fmaf(xv.w, w3.w, acc[3]);
    }

    // bias + LeakyReLU -> LDS
    {
        float4 hv;
        float* hp = (float*)&hv;
#pragma unroll
        for (int j = 0; j < 4; ++j) {
            float h = acc[j] + b_cpr[cc + j];
            hp[j] = (h >= 0.f) ? h : 0.01f * h;
        }
        *(float4*)&h_lds[rr][cc] = hv;
    }
    __syncthreads();

    // ---------------- head: K-split partial dots ----------------
    if (tid < BR * R_SZ * 4) {           // 224 threads: (bl, r, chunk)
        const int chunk = tid & 3;
        const int rh = (tid >> 2) % R_SZ;
        const int bl = tid / (R_SZ * 4);
        const float* wr = W_sm + rh * C_SZ;
        const int c0 = chunk * 64;
        float s = 0.f;
#pragma unroll
        for (int c = 0; c < 64; c += 4) {
            float4 hv = *(const float4*)&h_lds[bl][c0 + c];
            s = fmaf(hv.x, wr[c0 + c + 0], s);
            s = fmaf(hv.y, wr[c0 + c + 1], s);
            s = fmaf(hv.z, wr[c0 + c + 2], s);
            s = fmaf(hv.w, wr[c0 + c + 3], s);
        }
        part[bl][rh][chunk] = s;
    }
    __syncthreads();

    if (tid < BR * R_SZ) {               // 56 threads: combine + bias
        const int bl = tid / R_SZ;
        const int rh = tid % R_SZ;
        l_lds[bl][rh] = part[bl][rh][0] + part[bl][rh][1] +
                        part[bl][rh][2] + part[bl][rh][3] + b_sm[rh];
    }
    __syncthreads();

    // ---------------- log-softmax over R=7 ----------------
    if (tid < BR) {
        float m = -INFINITY;
#pragma unroll
        for (int rh = 0; rh < R_SZ; ++rh) m = fmaxf(m, l_lds[tid][rh]);
        float se = 0.f;
#pragma unroll
        for (int rh = 0; rh < R_SZ; ++rh) se += expf(l_lds[tid][rh] - m);
        const float lse = m + logf(se);
        const size_t ob = (size_t)(row0 + tid) * R_SZ;
#pragma unroll
        for (int rh = 0; rh < R_SZ; ++rh) out[ob + rh] = l_lds[tid][rh] - lse;
    }
}

// ---------------------------------------------------------------------------
extern "C" void kernel_launch(void* const* d_in, const int* in_sizes, int n_in,
                              void* d_out, int out_size, void* d_ws, size_t ws_size,
                              hipStream_t stream) {
    const int* ltok = (const int*)d_in[0];
    const int* rtok = (const int*)d_in[1];
    const int* lmask = (const int*)d_in[2];
    const int* rmask = (const int*)d_in[3];
    const float* emb = (const float*)d_in[4];
    const float* W_cpr = (const float*)d_in[5];
    const float* b_cpr = (const float*)d_in[6];
    const float* W_sm = (const float*)d_in[7];
    const float* b_sm = (const float*)d_in[8];
    float* out = (float*)d_out;

    float* Wt = (float*)d_ws;  // [K_SZ][C_SZ] = 256 KB

    k_transpose<<<dim3(K_SZ / 32, C_SZ / 32), 256, 0, stream>>>(W_cpr, Wt);
    k_fused<<<B_SZ / BR, NT, 0, stream>>>(ltok, rtok, lmask, rmask, emb, Wt,
                                          b_cpr, W_sm, b_sm, out);
}

// Round 6
// 69.614 us; speedup vs baseline: 1.5207x; 1.5207x over previous
//
#include <hip/hip_runtime.h>
#include <math.h>

// Problem constants (from reference)
#define B_SZ 8192
#define L_SZ 50
#define D_SZ 128
#define C_SZ 256        // output cols of W_cpr
#define K_SZ 256        // = 2*D, GEMM K
#define R_SZ 7
#define BR   32         // batch rows per block
#define NT   512        // 8 waves

// ---------------------------------------------------------------------------
// Kernel 0: transpose W_cpr [C][K] -> Wt [K][C], LDS-tiled. 256 KB, ~2 us.
// ---------------------------------------------------------------------------
__global__ __launch_bounds__(256) void k_transpose(const float* __restrict__ W,
                                                   float* __restrict__ Wt) {
    __shared__ float t[32][33];
    const int tx = threadIdx.x & 31;
    const int ty = threadIdx.x >> 5;  // 0..7
    const int k0 = blockIdx.x * 32;
    const int c0 = blockIdx.y * 32;
#pragma unroll
    for (int i = 0; i < 32; i += 8)
        t[ty + i][tx] = W[(size_t)(c0 + ty + i) * K_SZ + k0 + tx];
    __syncthreads();
#pragma unroll
    for (int i = 0; i < 32; i += 8)
        Wt[(size_t)(k0 + ty + i) * C_SZ + c0 + tx] = t[tx][ty + i];
}

// ---------------------------------------------------------------------------
// Fused kernel: masked embedding-bag sums (to LDS) + GEMM + LeakyReLU +
// 7-wide head + log-softmax.
//
// 512 threads = 8 waves, BR=32 rows/block (4 rows per wave in the gather).
// Gather: 8 ballot streams per wave (4 rows x 2 sides); each POP2 loads two
// tokens' rows (lanes 0-31 token A, 32-63 token B, float4 each) -> 8 x 1 KB
// loads in flight per wave.
// GEMM: 64 col-groups x 8 row-groups, acc[4][4] per thread (R=4 row reuse of
// each W load). All waves traverse Wt in the same k-order -> L1 temporal
// reuse; per-CU W delivery ~2 MB instead of R5's ~8 MB.
// ---------------------------------------------------------------------------
__global__ __launch_bounds__(512, 2) void k_fused(
    const int* __restrict__ ltok, const int* __restrict__ rtok,
    const int* __restrict__ lmask, const int* __restrict__ rmask,
    const float* __restrict__ emb, const float* __restrict__ Wt,
    const float* __restrict__ b_cpr, const float* __restrict__ W_sm,
    const float* __restrict__ b_sm, float* __restrict__ out) {

    __shared__ float X_lds[BR][K_SZ];        // 32 KB
    __shared__ float h_lds[BR][C_SZ + 4];    // 33.3 KB
    __shared__ float part[BR][R_SZ][2];
    __shared__ float l_lds[BR][R_SZ];

    const int tid = threadIdx.x;
    const int wave = tid >> 6;
    const int lane = tid & 63;
    const int hlane = lane & 31;
    const int row0 = blockIdx.x * BR;

    // ---------------- gather phase: 4 rows per wave ----------------
    const int rbase = row0 + wave * 4;
    int lt0 = 0, lt1 = 0, lt2 = 0, lt3 = 0;
    int rt0 = 0, rt1 = 0, rt2 = 0, rt3 = 0;
    int lm0 = 0, lm1 = 0, lm2 = 0, lm3 = 0;
    int rm0 = 0, rm1 = 0, rm2 = 0, rm3 = 0;
    if (lane < L_SZ) {
        const size_t o = (size_t)rbase * L_SZ + lane;
        lt0 = ltok[o];            lm0 = lmask[o];
        lt1 = ltok[o + L_SZ];     lm1 = lmask[o + L_SZ];
        lt2 = ltok[o + 2 * L_SZ]; lm2 = lmask[o + 2 * L_SZ];
        lt3 = ltok[o + 3 * L_SZ]; lm3 = lmask[o + 3 * L_SZ];
        rt0 = rtok[o];            rm0 = rmask[o];
        rt1 = rtok[o + L_SZ];     rm1 = rmask[o + L_SZ];
        rt2 = rtok[o + 2 * L_SZ]; rm2 = rmask[o + 2 * L_SZ];
        rt3 = rtok[o + 3 * L_SZ]; rm3 = rmask[o + 3 * L_SZ];
    }
    unsigned long long bL0 = __ballot(lm0 != 0), bL1 = __ballot(lm1 != 0);
    unsigned long long bL2 = __ballot(lm2 != 0), bL3 = __ballot(lm3 != 0);
    unsigned long long bR0 = __ballot(rm0 != 0), bR1 = __ballot(rm1 != 0);
    unsigned long long bR2 = __ballot(rm2 != 0), bR3 = __ballot(rm3 != 0);

    const float4* emb4 = (const float4*)emb;  // [V][32] float4
    float4 aL0 = {0, 0, 0, 0}, aL1 = {0, 0, 0, 0};
    float4 aL2 = {0, 0, 0, 0}, aL3 = {0, 0, 0, 0};
    float4 aR0 = {0, 0, 0, 0}, aR1 = {0, 0, 0, 0};
    float4 aR2 = {0, 0, 0, 0}, aR3 = {0, 0, 0, 0};

    // Pop up to 2 tokens of a stream: lanes 0-31 take the 1st set bit's
    // token, lanes 32-63 the 2nd (scale 0 if the stream had only one).
#define POP2(bal, tok, e, sc, hv)                                   \
    {                                                               \
        hv = (bal != 0);                                            \
        if (hv) {                                                   \
            int i1 = __ffsll(bal) - 1; bal &= bal - 1;              \
            bool has2 = (bal != 0);                                 \
            int i2 = has2 ? (__ffsll(bal) - 1) : i1;                \
            if (has2) bal &= bal - 1;                               \
            int ts = __shfl(tok, (lane < 32) ? i1 : i2);            \
            e = emb4[((unsigned)ts << 5) + hlane];                  \
            sc = (lane < 32 || has2) ? 1.f : 0.f;                   \
        }                                                           \
    }
#define ACC4(a, s, e)                                               \
    { a.x = fmaf(s, e.x, a.x); a.y = fmaf(s, e.y, a.y);             \
      a.z = fmaf(s, e.z, a.z); a.w = fmaf(s, e.w, a.w); }

    while (bL0 | bL1 | bL2 | bL3 | bR0 | bR1 | bR2 | bR3) {
        float4 e0, e1, e2, e3, e4, e5, e6, e7;
        float s0, s1, s2, s3, s4, s5, s6, s7;
        bool h0, h1, h2, h3, h4, h5, h6, h7;
        POP2(bL0, lt0, e0, s0, h0)
        POP2(bL1, lt1, e1, s1, h1)
        POP2(bL2, lt2, e2, s2, h2)
        POP2(bL3, lt3, e3, s3, h3)
        POP2(bR0, rt0, e4, s4, h4)
        POP2(bR1, rt1, e5, s5, h5)
        POP2(bR2, rt2, e6, s6, h6)
        POP2(bR3, rt3, e7, s7, h7)
        if (h0) ACC4(aL0, s0, e0)
        if (h1) ACC4(aL1, s1, e1)
        if (h2) ACC4(aL2, s2, e2)
        if (h3) ACC4(aL3, s3, e3)
        if (h4) ACC4(aR0, s4, e4)
        if (h5) ACC4(aR1, s5, e5)
        if (h6) ACC4(aR2, s6, e6)
        if (h7) ACC4(aR3, s7, e7)
    }
#undef POP2
#undef ACC4

    // cross-half reduce: every lane ends with the full token sum of chunk hlane
#define XHALF(a)                          \
    a.x += __shfl_xor(a.x, 32);           \
    a.y += __shfl_xor(a.y, 32);           \
    a.z += __shfl_xor(a.z, 32);           \
    a.w += __shfl_xor(a.w, 32);
    XHALF(aL0) XHALF(aL1) XHALF(aL2) XHALF(aL3)
    XHALF(aR0) XHALF(aR1) XHALF(aR2) XHALF(aR3)
#undef XHALF

    // X row layout: float4 slots [0,32) = left sum, [32,64) = right sum.
    // lanes 0-31 write the left half (chunk hlane), 32-63 the right half.
    {
        const int slot = (lane < 32) ? hlane : (32 + hlane);
        ((float4*)&X_lds[rbase - row0 + 0][0])[slot] = (lane < 32) ? aL0 : aR0;
        ((float4*)&X_lds[rbase - row0 + 1][0])[slot] = (lane < 32) ? aL1 : aR1;
        ((float4*)&X_lds[rbase - row0 + 2][0])[slot] = (lane < 32) ? aL2 : aR2;
        ((float4*)&X_lds[rbase - row0 + 3][0])[slot] = (lane < 32) ? aL3 : aR3;
    }
    __syncthreads();

    // ---------------- GEMM phase: 64 col-groups x 8 row-groups, R=4 --------
    const int cc = (tid & 63) * 4;        // 4 output cols
    const int rr = (tid >> 6) * 4;        // 4 rows
    float acc[4][4] = {{0.f}};
#pragma unroll 2
    for (int k = 0; k < K_SZ; k += 4) {
        float4 w0 = *(const float4*)&Wt[(k + 0) * C_SZ + cc];
        float4 w1 = *(const float4*)&Wt[(k + 1) * C_SZ + cc];
        float4 w2 = *(const float4*)&Wt[(k + 2) * C_SZ + cc];
        float4 w3 = *(const float4*)&Wt[(k + 3) * C_SZ + cc];
        float ws[4][4] = {{w0.x, w0.y, w0.z, w0.w}, {w1.x, w1.y, w1.z, w1.w},
                          {w2.x, w2.y, w2.z, w2.w}, {w3.x, w3.y, w3.z, w3.w}};
#pragma unroll
        for (int i = 0; i < 4; ++i) {
            float4 xv = *(const float4*)&X_lds[rr + i][k];  // broadcast
            float xs[4] = {xv.x, xv.y, xv.z, xv.w};
#pragma unroll
            for (int kk = 0; kk < 4; ++kk) {
#pragma unroll
                for (int j = 0; j < 4; ++j)
                    acc[i][j] = fmaf(xs[kk], ws[kk][j], acc[i][j]);
            }
        }
    }

    // bias + LeakyReLU -> LDS
#pragma unroll
    for (int i = 0; i < 4; ++i) {
        float4 hv;
        float* hp = (float*)&hv;
#pragma unroll
        for (int j = 0; j < 4; ++j) {
            float h = acc[i][j] + b_cpr[cc + j];
            hp[j] = (h >= 0.f) ? h : 0.01f * h;
        }
        *(float4*)&h_lds[rr + i][cc] = hv;
    }
    __syncthreads();

    // ---------------- head: K-split partial dots (2 chunks of 128) --------
    if (tid < BR * R_SZ * 2) {            // 448 threads: (bl, r, chunk)
        const int chunk = tid & 1;
        const int rh = (tid >> 1) % R_SZ;
        const int bl = tid / (R_SZ * 2);
        const float* wr = W_sm + rh * C_SZ;
        const int c0 = chunk * 128;
        float s = 0.f;
#pragma unroll
        for (int c = 0; c < 128; c += 4) {
            float4 hv = *(const float4*)&h_lds[bl][c0 + c];
            s = fmaf(hv.x, wr[c0 + c + 0], s);
            s = fmaf(hv.y, wr[c0 + c + 1], s);
            s = fmaf(hv.z, wr[c0 + c + 2], s);
            s = fmaf(hv.w, wr[c0 + c + 3], s);
        }
        part[bl][rh][chunk] = s;
    }
    __syncthreads();

    if (tid < BR * R_SZ) {                // 224 threads: combine + bias
        const int bl = tid / R_SZ;
        const int rh = tid % R_SZ;
        l_lds[bl][rh] = part[bl][rh][0] + part[bl][rh][1] + b_sm[rh];
    }
    __syncthreads();

    // ---------------- log-softmax over R=7 ----------------
    if (tid < BR) {
        float m = -INFINITY;
#pragma unroll
        for (int rh = 0; rh < R_SZ; ++rh) m = fmaxf(m, l_lds[tid][rh]);
        float se = 0.f;
#pragma unroll
        for (int rh = 0; rh < R_SZ; ++rh) se += expf(l_lds[tid][rh] - m);
        const float lse = m + logf(se);
        const size_t ob = (size_t)(row0 + tid) * R_SZ;
#pragma unroll
        for (int rh = 0; rh < R_SZ; ++rh) out[ob + rh] = l_lds[tid][rh] - lse;
    }
}

// ---------------------------------------------------------------------------
extern "C" void kernel_launch(void* const* d_in, const int* in_sizes, int n_in,
                              void* d_out, int out_size, void* d_ws, size_t ws_size,
                              hipStream_t stream) {
    const int* ltok = (const int*)d_in[0];
    const int* rtok = (const int*)d_in[1];
    const int* lmask = (const int*)d_in[2];
    const int* rmask = (const int*)d_in[3];
    const float* emb = (const float*)d_in[4];
    const float* W_cpr = (const float*)d_in[5];
    const float* b_cpr = (const float*)d_in[6];
    const float* W_sm = (const float*)d_in[7];
    const float* b_sm = (const float*)d_in[8];
    float* out = (float*)d_out;

    float* Wt = (float*)d_ws;  // [K_SZ][C_SZ] = 256 KB

    k_transpose<<<dim3(K_SZ / 32, C_SZ / 32), 256, 0, stream>>>(W_cpr, Wt);
    k_fused<<<B_SZ / BR, NT, 0, stream>>>(ltok, rtok, lmask, rmask, emb, Wt,
                                          b_cpr, W_sm, b_sm, out);
}